// Round 7
// baseline (498.191 us; speedup 1.0000x reference)
//
#include <hip/hip_runtime.h>

typedef __attribute__((ext_vector_type(8))) short short8;
typedef __attribute__((ext_vector_type(16))) float f32x16;
typedef __attribute__((ext_vector_type(4))) unsigned short us4;

#define MFMA32(a,b,c) __builtin_amdgcn_mfma_f32_32x32x16_bf16((a),(b),(c),0,0,0)

__device__ __forceinline__ unsigned short f2bf(float f) {
  union { float f; unsigned u; } v; v.f = f;
  return (unsigned short)((v.u + 0x7fffu + ((v.u >> 16) & 1u)) >> 16);
}
__device__ __forceinline__ float bf2f(unsigned short h) {
  union { unsigned u; float f; } v; v.u = ((unsigned)h) << 16;
  return v.f;
}
__device__ __forceinline__ f32x16 zero16() {
  f32x16 v;
  #pragma unroll
  for (int i = 0; i < 16; ++i) v[i] = 0.f;
  return v;
}
__device__ __forceinline__ void gload16(const void* g, void* l) {
  __builtin_amdgcn_global_load_lds(
      (const __attribute__((address_space(1))) void*)(g),
      (__attribute__((address_space(3))) void*)(l), 16, 0, 0);
}

// ---------------- prep: weights -> bf16 fragment-major layouts --------------
//   frag[unit][ks][lane*8+e] = W[k = ks*16 + (lane>>5)*8 + e][col = base + (lane&31)]
// wtcf: [29 taps][2 nhalf][12 ks][512]   (conv, K=192)
// w1f : [3 nt][20 ks][512]  cols 80..95 zero-padded (att1, K=320)
// w2f : [10 nt][6 ks][512]  k 80..95 zero-padded    (att2, K=96)
// wof : [10 nt][20 ks][512]                          (out,  K=320)
__global__ __launch_bounds__(256) void k_prep(
    const float* __restrict__ w1, const float* __restrict__ w2,
    const float* __restrict__ w3, const float* __restrict__ w4,
    const float* __restrict__ w5,
    const float* __restrict__ b1, const float* __restrict__ b2,
    const float* __restrict__ b3, const float* __restrict__ b4,
    const float* __restrict__ b5,
    const float* __restrict__ wa1, const float* __restrict__ wa2,
    const float* __restrict__ wo,
    unsigned short* __restrict__ wtcf, unsigned short* __restrict__ w1f,
    unsigned short* __restrict__ w2f, unsigned short* __restrict__ wof,
    float* __restrict__ bcat)
{
  int i = blockIdx.x * 256 + threadIdx.x;
  if (i < 356352) {                       // conv weights
    int e = i & 7, l = (i >> 3) & 63, ks = (i >> 9) % 12;
    int rest = i / 6144; int nt2 = rest & 1, t = rest >> 1;
    int k = ks * 16 + (l >> 5) * 8 + e;   // 0..191
    int n = nt2 * 32 + (l & 31);          // 0..63
    const float* w; int j;
    if (t < 3)       { w = w1; j = t; }
    else if (t < 6)  { w = w2; j = t - 3; }
    else if (t < 11) { w = w3; j = t - 6; }
    else if (t < 20) { w = w4; j = t - 11; }
    else             { w = w5; j = t - 20; }
    wtcf[i] = f2bf(w[(j * 192 + k) * 64 + n]);
    return;
  }
  i -= 356352;
  if (i < 30720) {                        // w1f
    int e = i & 7, l = (i >> 3) & 63, ks = (i >> 9) % 20, nt = i / 10240;
    int h = nt * 32 + (l & 31), k = ks * 16 + (l >> 5) * 8 + e;
    w1f[i] = (h < 80) ? f2bf(wa1[k * 80 + h]) : (unsigned short)0;
    return;
  }
  i -= 30720;
  if (i < 30720) {                        // w2f
    int e = i & 7, l = (i >> 3) & 63, ks = (i >> 9) % 6, nt = i / 3072;
    int f = nt * 32 + (l & 31), k = ks * 16 + (l >> 5) * 8 + e;
    w2f[i] = (k < 80) ? f2bf(wa2[k * 320 + f]) : (unsigned short)0;
    return;
  }
  i -= 30720;
  if (i < 102400) {                       // wof
    int e = i & 7, l = (i >> 3) & 63, ks = (i >> 9) % 20, nt = i / 10240;
    int g = nt * 32 + (l & 31), k = ks * 16 + (l >> 5) * 8 + e;
    wof[i] = f2bf(wo[k * 320 + g]);
    return;
  }
  i -= 102400;
  if (i < 320) {
    float v;
    if (i < 64)       v = b1[i];
    else if (i < 128) v = b2[i - 64];
    else if (i < 192) v = b3[i - 128];
    else if (i < 256) v = b4[i - 192];
    else              v = b5[i - 256];
    bcat[i] = v;
  }
}

// ---------------- xpad: x fp32 -> bf16, [32][4192 rows][200 shorts] ---------
// Rows 0..95 of each batch are the causal zero-pad; row 96+t = x[b][t].
// Row stride 400 B (16B-aligned, == LDS stride -> staging is linear DMA).
__global__ __launch_bounds__(256) void k_xpad(
    const float* __restrict__ x, unsigned short* __restrict__ xpad)
{
  int i = blockIdx.x * 256 + threadIdx.x;     // one us4 (4 shorts) each
  if (i >= 32 * 4192 * 50) return;
  int c4 = i % 50; int rest = i / 50;
  int r = rest % 4192; int b = rest / 4192;
  us4 o = {0, 0, 0, 0};
  if (r >= 96 && c4 < 48) {
    float4 v = *(const float4*)(x + ((size_t)(b * 4096 + r - 96) * 192 + c4 * 4));
    o[0] = f2bf(v.x); o[1] = f2bf(v.y); o[2] = f2bf(v.z); o[3] = f2bf(v.w);
  }
  *(us4*)(xpad + (size_t)(b * 4192 + r) * 200 + c4 * 4) = o;
}

// ---------------- fused conv -> gate -> out ---------------------------------
// M=64, 512 thr (8 waves), 2 blocks/CU. LDS union (67584 B):
//   phase A: x window [160 rows][400 B]  (+staging overrun to 65536)
//   phase B: xc [64][784 B] @0  +  a1 [64][272 B] @50176
// All strides = 4 dwords mod 32 -> bank-balanced, conflict-free.
#define XC_S 392   // xc row stride in shorts (784 B)
#define A1_S 136   // a1 row stride in shorts (272 B)
#define A1_OFF 50176

template<int KT, int DL, int TB>
__device__ __forceinline__ void conv_unit(
    const unsigned short* __restrict__ xsS,
    const unsigned short* __restrict__ wtcf,
    int nh, int l31, int lh, int lane, f32x16& acc0, f32x16& acc1)
{
  const int r0 = 96 + l31;
  #pragma unroll
  for (int j = 0; j < KT; ++j) {
    const int row = r0 - DL * (KT - 1 - j);           // causal offset
    const unsigned short* xr = xsS + row * 200 + lh * 8;
    const unsigned short* wp = wtcf + (size_t)((TB + j) * 2 + nh) * 6144 + lane * 8;
    #pragma unroll
    for (int half = 0; half < 2; ++half) {
      short8 breg[6];
      #pragma unroll
      for (int ks = 0; ks < 6; ++ks)
        breg[ks] = *(const short8*)(wp + (half * 6 + ks) * 512);
      #pragma unroll
      for (int ks = 0; ks < 6; ++ks) {
        const int kk = half * 6 + ks;
        short8 a0 = *(const short8*)(xr + kk * 16);
        short8 a1 = *(const short8*)(xr + 32 * 200 + kk * 16);
        acc0 = MFMA32(a0, breg[ks], acc0);
        acc1 = MFMA32(a1, breg[ks], acc1);
      }
    }
  }
}

__global__ __launch_bounds__(512, 4) void k_fused(
    const unsigned short* __restrict__ xpad,
    const unsigned short* __restrict__ wtcf,
    const unsigned short* __restrict__ w1f, const unsigned short* __restrict__ w2f,
    const unsigned short* __restrict__ wof, const float* __restrict__ bcat,
    const float* __restrict__ ba1, const float* __restrict__ ba2,
    const float* __restrict__ bo, float* __restrict__ out)
{
  __shared__ __align__(16) unsigned char smem[67584];
  int bid = blockIdx.x;
  bid = (bid & 7) * 256 + (bid >> 3);          // XCD swizzle (2048 % 8 == 0)
  const int m0 = bid * 64;
  const int b  = m0 >> 12;
  const int t0 = m0 & 4095;
  const int tid = threadIdx.x;
  const int wid = tid >> 6, lane = tid & 63;
  const int l31 = lane & 31, lh = lane >> 5;

  // ---- stage x window rows [t0-96, t0+64): pure linear DMA (65536 B) ----
  {
    const unsigned char* xsrc =
        (const unsigned char*)(xpad + ((size_t)b * 4192 + t0) * 200);
    #pragma unroll
    for (int it = 0; it < 8; ++it) {
      int off = (tid + it * 512) * 16;
      gload16(xsrc + off, smem + off);
    }
  }
  __syncthreads();

  // ---- conv into registers: units (br, nh), taps {9,9,9,9,5,5,3+3,3+3} ----
  f32x16 c0a = zero16(), c0b = zero16(), c1a = zero16(), c1b = zero16();
  const int nh = wid & 1;
  {
    const unsigned short* xsS = (const unsigned short*)smem;
    switch (wid >> 1) {
      case 0: conv_unit<9,12,20>(xsS, wtcf, nh, l31, lh, lane, c0a, c0b); break;
      case 1: conv_unit<9, 8,11>(xsS, wtcf, nh, l31, lh, lane, c0a, c0b); break;
      case 2: conv_unit<5, 4, 6>(xsS, wtcf, nh, l31, lh, lane, c0a, c0b); break;
      default:
        conv_unit<3, 2, 3>(xsS, wtcf, nh, l31, lh, lane, c0a, c0b);
        conv_unit<3, 1, 0>(xsS, wtcf, nh, l31, lh, lane, c1a, c1b);
        break;
    }
  }
  __syncthreads();                             // all x reads done

  // ---- write xc (relu + bias) into LDS @0 ----
  {
    unsigned short* xcS = (unsigned short*)smem;
    const int brmap = (wid >> 1 == 0) ? 4 : (wid >> 1 == 1) ? 3 :
                      (wid >> 1 == 2) ? 2 : 1;
    const int col0 = (brmap * 2 + nh) * 32 + l31;
    const float bias0 = bcat[col0];
    #pragma unroll
    for (int r = 0; r < 16; ++r) {
      int row = (r & 3) + 8 * (r >> 2) + 4 * lh;
      float v0 = c0a[r] + bias0; v0 = v0 > 0.f ? v0 : 0.f;
      float v1 = c0b[r] + bias0; v1 = v1 > 0.f ? v1 : 0.f;
      xcS[row * XC_S + col0]        = f2bf(v0);
      xcS[(row + 32) * XC_S + col0] = f2bf(v1);
    }
    if ((wid >> 1) == 3) {                     // second unit: br0
      const int col1 = (0 * 2 + nh) * 32 + l31;
      const float bias1 = bcat[col1];
      #pragma unroll
      for (int r = 0; r < 16; ++r) {
        int row = (r & 3) + 8 * (r >> 2) + 4 * lh;
        float v0 = c1a[r] + bias1; v0 = v0 > 0.f ? v0 : 0.f;
        float v1 = c1b[r] + bias1; v1 = v1 > 0.f ? v1 : 0.f;
        xcS[row * XC_S + col1]        = f2bf(v0);
        xcS[(row + 32) * XC_S + col1] = f2bf(v1);
      }
    }
  }
  __syncthreads();                             // xc visible

  const unsigned short* xcS = (const unsigned short*)smem;
  unsigned short* a1S = (unsigned short*)(smem + A1_OFF);

  // ---- ph1: att1 = relu(xc @ W1 + b1) -> a1 (waves 0-5: (nt, mt)) ----
  if (wid < 6) {
    const int nt = wid >> 1, mt = wid & 1;
    f32x16 acc = zero16();
    const unsigned short* ar = xcS + (mt * 32 + l31) * XC_S + lh * 8;
    const unsigned short* bp = w1f + (size_t)(nt * 20) * 512 + lane * 8;
    #pragma unroll
    for (int ks = 0; ks < 20; ++ks) {
      short8 af = *(const short8*)(ar + ks * 16);
      short8 bf = *(const short8*)(bp + ks * 512);
      acc = MFMA32(af, bf, acc);
    }
    const int h = nt * 32 + l31;
    const float bias = (h < 80) ? ba1[h] : 0.f;
    #pragma unroll
    for (int r = 0; r < 16; ++r) {
      int row = mt * 32 + (r & 3) + 8 * (r >> 2) + 4 * lh;
      float v = acc[r] + bias; v = v > 0.f ? v : 0.f;
      a1S[row * A1_S + h] = f2bf(v);
    }
  }
  __syncthreads();

  // ---- ph2: att2 = sigmoid(a1 @ W2 + b2); xc *= att2 in-LDS ----
  // wave -> (mt = wid&1) rows, col tiles {c0, c0+4, c0+8<10} where c0 = wid>>1
  const int mt2 = wid & 1, cw = wid >> 1;
  {
    f32x16 q0 = zero16(), q1 = zero16(), q2 = zero16();
    const unsigned short* ar = a1S + (mt2 * 32 + l31) * A1_S + lh * 8;
    #pragma unroll
    for (int ks = 0; ks < 6; ++ks) {
      short8 af = *(const short8*)(ar + ks * 16);
      short8 b0 = *(const short8*)(w2f + (size_t)((cw    ) * 6 + ks) * 512 + lane * 8);
      short8 b1 = *(const short8*)(w2f + (size_t)((cw + 4) * 6 + ks) * 512 + lane * 8);
      q0 = MFMA32(af, b0, q0);
      q1 = MFMA32(af, b1, q1);
      if (cw < 2) {
        short8 b2v = *(const short8*)(w2f + (size_t)((cw + 8) * 6 + ks) * 512 + lane * 8);
        q2 = MFMA32(af, b2v, q2);
      }
    }
    unsigned short* xcW = (unsigned short*)smem;
    #pragma unroll
    for (int t = 0; t < 3; ++t) {
      if (t == 2 && cw >= 2) break;
      const f32x16& Q = (t == 0) ? q0 : (t == 1) ? q1 : q2;
      const int c = cw + 4 * t;
      const float bias = ba2[c * 32 + l31];
      #pragma unroll
      for (int r = 0; r < 16; ++r) {
        int row = mt2 * 32 + (r & 3) + 8 * (r >> 2) + 4 * lh;
        float v = Q[r] + bias;
        float s = 1.f / (1.f + __expf(-v));
        unsigned short* p = xcW + row * XC_S + c * 32 + l31;
        *p = f2bf(bf2f(*p) * s);
      }
    }
  }
  __syncthreads();

  // ---- out = xa @ W_out + b_out (same unit map as ph2) ----
  {
    f32x16 o0 = zero16(), o1 = zero16(), o2 = zero16();
    const unsigned short* ar = xcS + (mt2 * 32 + l31) * XC_S + lh * 8;
    #pragma unroll
    for (int ks = 0; ks < 20; ++ks) {
      short8 af = *(const short8*)(ar + ks * 16);
      short8 b0 = *(const short8*)(wof + (size_t)((cw    ) * 20 + ks) * 512 + lane * 8);
      short8 b1 = *(const short8*)(wof + (size_t)((cw + 4) * 20 + ks) * 512 + lane * 8);
      o0 = MFMA32(af, b0, o0);
      o1 = MFMA32(af, b1, o1);
      if (cw < 2) {
        short8 b2v = *(const short8*)(wof + (size_t)((cw + 8) * 20 + ks) * 512 + lane * 8);
        o2 = MFMA32(af, b2v, o2);
      }
    }
    #pragma unroll
    for (int t = 0; t < 3; ++t) {
      if (t == 2 && cw >= 2) break;
      const f32x16& O = (t == 0) ? o0 : (t == 1) ? o1 : o2;
      const int c = cw + 4 * t;
      const float bias = bo[c * 32 + l31];
      #pragma unroll
      for (int r = 0; r < 16; ++r) {
        int row = mt2 * 32 + (r & 3) + 8 * (r >> 2) + 4 * lh;
        out[(size_t)(m0 + row) * 320 + c * 32 + l31] = O[r] + bias;
      }
    }
  }
}

// ---------------- host ------------------------------------------------------
extern "C" void kernel_launch(void* const* d_in, const int* in_sizes, int n_in,
                              void* d_out, int out_size, void* d_ws, size_t ws_size,
                              hipStream_t stream) {
  const float* x    = (const float*)d_in[0];
  const float* w_b1 = (const float*)d_in[1];  const float* b_b1 = (const float*)d_in[2];
  const float* w_b2 = (const float*)d_in[3];  const float* b_b2 = (const float*)d_in[4];
  const float* w_b3 = (const float*)d_in[5];  const float* b_b3 = (const float*)d_in[6];
  const float* w_b4 = (const float*)d_in[7];  const float* b_b4 = (const float*)d_in[8];
  const float* w_b5 = (const float*)d_in[9];  const float* b_b5 = (const float*)d_in[10];
  const float* wa1  = (const float*)d_in[11]; const float* ba1  = (const float*)d_in[12];
  const float* wa2  = (const float*)d_in[13]; const float* ba2  = (const float*)d_in[14];
  const float* wo   = (const float*)d_in[15]; const float* bo   = (const float*)d_in[16];

  char* ws = (char*)d_ws;
  unsigned short* wtcf = (unsigned short*)(ws);             // 712,704 B
  unsigned short* w1f  = (unsigned short*)(ws + 712704);    // 61,440
  unsigned short* w2f  = (unsigned short*)(ws + 774144);    // 61,440
  unsigned short* wof  = (unsigned short*)(ws + 835584);    // 204,800
  float*          bct  = (float*)         (ws + 1040384);   // 1,280
  unsigned short* xpad = (unsigned short*)(ws + 1041664);   // 32*4192*400 + 3200 B

  k_prep<<<2034, 256, 0, stream>>>(w_b1, w_b2, w_b3, w_b4, w_b5,
                                   b_b1, b_b2, b_b3, b_b4, b_b5,
                                   wa1, wa2, wo, wtcf, w1f, w2f, wof, bct);
  k_xpad<<<26200, 256, 0, stream>>>(x, xpad);
  k_fused<<<2048, 512, 0, stream>>>(xpad, wtcf, w1f, w2f, wof, bct,
                                    ba1, ba2, bo, (float*)d_out);
}